// Round 6
// baseline (155.896 us; speedup 1.0000x reference)
//
#include <hip/hip_runtime.h>
#include <hip/hip_bf16.h>

#define B_  8
#define T_  2048
#define C_  1024
#define H_  128

using f32x4  = __attribute__((ext_vector_type(4))) float;
using bf16x8 = __attribute__((ext_vector_type(8))) short;

__device__ __forceinline__ unsigned short f2bf(float f) {
    union { float f; unsigned u; } v; v.f = f;
    unsigned r = v.u + 0x7FFFu + ((v.u >> 16) & 1u);   // RNE
    return (unsigned short)(r >> 16);
}

// counted barrier: LDS visibility only; leaves global loads in flight (T4)
#define BAR() do { asm volatile("s_waitcnt lgkmcnt(0)" ::: "memory"); \
                   __builtin_amdgcn_s_barrier(); } while (0)

// DPP cross-lane reduce within 16-lane rows (VALU-speed)
template<int C>
__device__ __forceinline__ float dppf(float v) {
    return __int_as_float(__builtin_amdgcn_update_dpp(0, __float_as_int(v), C, 0xF, 0xF, true));
}
#define DPPRED_MAX(v) { v = fmaxf(v, dppf<0xB1>(v)); v = fmaxf(v, dppf<0x4E>(v)); \
                        v = fmaxf(v, dppf<0x141>(v)); v = fmaxf(v, dppf<0x140>(v)); }
#define DPPRED_SUM(v) { v = v + dppf<0xB1>(v); v = v + dppf<0x4E>(v); \
                        v = v + dppf<0x141>(v); v = v + dppf<0x140>(v); }

// ---------------------------------------------------------------------------
// W{q,k,v} fp32 [1024][128] -> Wt bf16 [384 cols][1024 k], Wq pre-scaled 1/32
// ---------------------------------------------------------------------------
__global__ void wconv_kernel(const float* __restrict__ Wq,
                             const float* __restrict__ Wk,
                             const float* __restrict__ Wv,
                             unsigned short* __restrict__ Wt) {
    int id  = blockIdx.x * 256 + threadIdx.x;
    int col = id % 384;
    int k   = id / 384;
    const float* W = (col < 128) ? Wq : ((col < 256) ? Wk : Wv);
    float v = W[k * H_ + (col & 127)];
    if (col < 128) v *= 0.03125f;   // fold C^-0.5 into Wq (exact pow2)
    Wt[(size_t)col * C_ + k] = f2bf(v);
}

// ---------------------------------------------------------------------------
// Fused projection GEMM. 512 blocks (64-row x 192-col half) x 512 thr (8 waves,
// wave = 16r x 96c). BK=64, 16 steps. As bf16 [2][64][64], 16B-chunk XOR
// swizzle. x prefetched 2 steps ahead, B issued at step top; counted barriers
// keep all global loads in flight across steps. 2 blocks/CU.
// ---------------------------------------------------------------------------
__launch_bounds__(512, 4)
__global__ void gemm_kernel(const float* __restrict__ x,
                            const unsigned short* __restrict__ Wt,
                            unsigned short* __restrict__ qb,
                            unsigned short* __restrict__ kb,
                            unsigned short* __restrict__ vT) {
    __shared__ unsigned short As[2][64][64];   // XOR-swizzled 16B chunks

    const int tid  = threadIdx.x;
    const int wave = tid >> 6;
    const int lane = tid & 63;
    const int lo = lane & 15, hi = lane >> 4;
    const int rb   = blockIdx.x >> 1;
    const int ch   = blockIdx.x & 1;
    const int row0 = rb * 64;
    const int col0 = ch * 192 + (wave & 1) * 96;
    const int wrow = (wave >> 1) * 16;

    const int srow = tid >> 3;                 // 0..63
    const int schk = tid & 7;                  // 0..7
    const float* xsrc = x + (size_t)(row0 + srow) * C_ + schk * 8;
    unsigned short* sdst[2] = {
        &As[0][srow][(schk ^ (srow & 7)) * 8],
        &As[1][srow][(schk ^ (srow & 7)) * 8]
    };
    const int arow = wrow + lo;                // A-frag row in tile
    const int abase0 = ((0 * 4 + hi) ^ (arow & 7)) * 8;   // kc=0 chunk
    const int abase1 = ((1 * 4 + hi) ^ (arow & 7)) * 8;   // kc=1 chunk

    f32x4 acc[6];
    #pragma unroll
    for (int ct = 0; ct < 6; ++ct) acc[ct] = f32x4{0.f, 0.f, 0.f, 0.f};

    // prologue: stage step 0; issue x for step 1
    {
        float4 g0 = *(const float4*)(xsrc);
        float4 g1 = *(const float4*)(xsrc + 4);
        unsigned a0 = f2bf(g0.x) | ((unsigned)f2bf(g0.y) << 16);
        unsigned a1 = f2bf(g0.z) | ((unsigned)f2bf(g0.w) << 16);
        unsigned a2 = f2bf(g1.x) | ((unsigned)f2bf(g1.y) << 16);
        unsigned a3 = f2bf(g1.z) | ((unsigned)f2bf(g1.w) << 16);
        *(uint4*)sdst[0] = uint4{a0, a1, a2, a3};
    }
    float4 h0 = *(const float4*)(xsrc + 64);
    float4 h1 = *(const float4*)(xsrc + 68);
    BAR();

    for (int k = 0; k < 16; ++k) {
        const int cur = k & 1;

        // B frags for this step (L2-resident; latency covered by 4 waves/SIMD)
        bf16x8 bf[6][2];
        #pragma unroll
        for (int ct = 0; ct < 6; ++ct) {
            const unsigned short* wp = Wt + (size_t)(col0 + ct * 16 + lo) * C_ + k * 64 + 8 * hi;
            bf[ct][0] = *(const bf16x8*)(wp);
            bf[ct][1] = *(const bf16x8*)(wp + 32);
        }
        // x loads for step k+2 (stay in flight across the barrier)
        float4 n0, n1;
        if (k < 14) {
            n0 = *(const float4*)(xsrc + (k + 2) * 64);
            n1 = *(const float4*)(xsrc + (k + 2) * 64 + 4);
        }

        // A frags from LDS
        bf16x8 af0 = *(const bf16x8*)&As[cur][arow][abase0];
        bf16x8 af1 = *(const bf16x8*)&As[cur][arow][abase1];

        #pragma unroll
        for (int ct = 0; ct < 6; ++ct)
            acc[ct] = __builtin_amdgcn_mfma_f32_16x16x32_bf16(af0, bf[ct][0], acc[ct], 0, 0, 0);
        #pragma unroll
        for (int ct = 0; ct < 6; ++ct)
            acc[ct] = __builtin_amdgcn_mfma_f32_16x16x32_bf16(af1, bf[ct][1], acc[ct], 0, 0, 0);

        // stage step k+1 (data loaded at step k-1; counted vmcnt by compiler)
        if (k < 15) {
            unsigned a0 = f2bf(h0.x) | ((unsigned)f2bf(h0.y) << 16);
            unsigned a1 = f2bf(h0.z) | ((unsigned)f2bf(h0.w) << 16);
            unsigned a2 = f2bf(h1.x) | ((unsigned)f2bf(h1.y) << 16);
            unsigned a3 = f2bf(h1.z) | ((unsigned)f2bf(h1.w) << 16);
            *(uint4*)sdst[cur ^ 1] = uint4{a0, a1, a2, a3};
        }
        BAR();
        h0 = n0; h1 = n1;
    }

    #pragma unroll
    for (int ct = 0; ct < 6; ++ct) {
        int col = col0 + ct * 16 + lo;
        int head = col >> 7;
        int h = col & 127;
        #pragma unroll
        for (int r = 0; r < 4; ++r) {
            int rg = row0 + wrow + 4 * hi + r;
            unsigned short val = f2bf(acc[ct][r]);
            if (head == 0)      qb[(size_t)rg * H_ + h] = val;
            else if (head == 1) kb[(size_t)rg * H_ + h] = val;
            else {
                int b = rg >> 11, t = rg & (T_ - 1);
                vT[((size_t)b * H_ + h) * T_ + t] = val;
            }
        }
    }
}

// ---------------------------------------------------------------------------
// Flash pass 1. Block = 8 waves (512 thr); QBLK=256 (32 q-rows/wave);
// chunk = 256 kv = 4 x KV64 tiles. Grid 512 (heavy qt first), empties exit.
// K/V staged in XOR-swizzled LDS; reg-staged one tile ahead with counted
// barriers (prefetch stays in flight). Per-wave guard skips masked tiles.
// ---------------------------------------------------------------------------
__launch_bounds__(512, 2)
__global__ void attn1_kernel(const unsigned short* __restrict__ qb,
                             const unsigned short* __restrict__ kb,
                             const unsigned short* __restrict__ vT,
                             float* __restrict__ Opart,
                             float* __restrict__ MLpart) {
    __shared__ unsigned short Ks[64 * 128];   // [kv][k], 16B chunks XOR-swizzled
    __shared__ unsigned short Vs[128 * 64];   // [h][kv], swizzled
    __shared__ unsigned short Ps[8][16][72];  // per-wave P transpose (2-pass)

    const int tid  = threadIdx.x;
    const int wave = tid >> 6;
    const int lane = tid & 63;
    const int lo = lane & 15, hi = lane >> 4;

    const int bid   = blockIdx.x;
    const int b     = bid & 7;
    const int chunk = (bid >> 3) & 7;
    const int qt    = 7 - (bid >> 6);
    if (chunk > qt) return;

    const int kv_begin = chunk << 8;
    const size_t bT = (size_t)b * T_;
    const int qrow0 = (qt << 8) + wave * 32;

    // staging assignment: K 2x16B chunks, V 2x16B chunks per thread
    const int krow = tid >> 3, kcol = (tid & 7) * 2;
    const int vrow = tid >> 2, vcol = (tid & 3) * 2;
    const unsigned short* kgsrc = kb + (bT + krow) * H_ + kcol * 8;
    const unsigned short* vgsrc = vT + ((size_t)b * H_ + vrow) * T_ + vcol * 8;
    unsigned short* kdst0 = &Ks[krow * 128 + ((kcol ^ (krow & 7)) * 8)];
    unsigned short* kdst1 = &Ks[krow * 128 + (((kcol + 1) ^ (krow & 7)) * 8)];
    unsigned short* vdst0 = &Vs[vrow * 64 + ((vcol ^ (vrow & 7)) * 8)];
    unsigned short* vdst1 = &Vs[vrow * 64 + (((vcol + 1) ^ (vrow & 7)) * 8)];

    // Q fragments (32 rows/wave)
    bf16x8 qf[2][4];
    #pragma unroll
    for (int q2 = 0; q2 < 2; ++q2)
        #pragma unroll
        for (int kc = 0; kc < 4; ++kc)
            qf[q2][kc] = *(const bf16x8*)(qb + (bT + qrow0 + 16 * q2 + lo) * H_ + kc * 32 + 8 * hi);

    float m[2][4], l[2][4];
    f32x4 o[2][8];
    #pragma unroll
    for (int q2 = 0; q2 < 2; ++q2)
        #pragma unroll
        for (int r = 0; r < 4; ++r) { m[q2][r] = -1e30f; l[q2][r] = 0.f; }
    #pragma unroll
    for (int q2 = 0; q2 < 2; ++q2)
        #pragma unroll
        for (int ct = 0; ct < 8; ++ct) o[q2][ct] = f32x4{0.f, 0.f, 0.f, 0.f};

    // prologue: stage-regs for tile 0
    uint4 kr0 = *(const uint4*)(kgsrc + (size_t)kv_begin * H_);
    uint4 kr1 = *(const uint4*)(kgsrc + (size_t)kv_begin * H_ + 8);
    uint4 vr0 = *(const uint4*)(vgsrc + kv_begin);
    uint4 vr1 = *(const uint4*)(vgsrc + kv_begin + 8);

    for (int t = 0; t < 4; ++t) {
        const int kv0 = kv_begin + t * 64;
        BAR();                                 // all reads of prev tile done
        *(uint4*)kdst0 = kr0;
        *(uint4*)kdst1 = kr1;
        *(uint4*)vdst0 = vr0;
        *(uint4*)vdst1 = vr1;
        BAR();                                 // tile staged
        if (t < 3) {                           // next-tile loads: fly across BARs
            const int kvn = kv0 + 64;
            kr0 = *(const uint4*)(kgsrc + (size_t)kvn * H_);
            kr1 = *(const uint4*)(kgsrc + (size_t)kvn * H_ + 8);
            vr0 = *(const uint4*)(vgsrc + kvn);
            vr1 = *(const uint4*)(vgsrc + kvn + 8);
        }
        if (kv0 > qrow0 + 31) continue;        // fully masked for this wave

        // S = Q K^T
        f32x4 s[2][4];
        #pragma unroll
        for (int q2 = 0; q2 < 2; ++q2)
            #pragma unroll
            for (int ct4 = 0; ct4 < 4; ++ct4) s[q2][ct4] = f32x4{0.f, 0.f, 0.f, 0.f};
        __builtin_amdgcn_s_setprio(1);
        #pragma unroll
        for (int ct4 = 0; ct4 < 4; ++ct4) {
            const int row = ct4 * 16 + lo;
            #pragma unroll
            for (int kc = 0; kc < 4; ++kc) {
                bf16x8 kf = *(const bf16x8*)&Ks[row * 128 + (((kc * 4 + hi) ^ (row & 7)) * 8)];
                s[0][ct4] = __builtin_amdgcn_mfma_f32_16x16x32_bf16(qf[0][kc], kf, s[0][ct4], 0, 0, 0);
                s[1][ct4] = __builtin_amdgcn_mfma_f32_16x16x32_bf16(qf[1][kc], kf, s[1][ct4], 0, 0, 0);
            }
        }
        __builtin_amdgcn_s_setprio(0);

        // causal mask (diagonal tiles only)
        if (kv0 + 63 >= qrow0) {
            #pragma unroll
            for (int q2 = 0; q2 < 2; ++q2)
                #pragma unroll
                for (int ct4 = 0; ct4 < 4; ++ct4)
                    #pragma unroll
                    for (int r = 0; r < 4; ++r)
                        if (kv0 + ct4 * 16 + lo > qrow0 + 16 * q2 + 4 * hi + r)
                            s[q2][ct4][r] = -1e30f;
        }

        // online softmax (DPP reductions within 16-lane rows)
        float alpha[2][4];
        #pragma unroll
        for (int q2 = 0; q2 < 2; ++q2) {
            #pragma unroll
            for (int r = 0; r < 4; ++r) {
                float pm = fmaxf(fmaxf(s[q2][0][r], s[q2][1][r]), fmaxf(s[q2][2][r], s[q2][3][r]));
                DPPRED_MAX(pm);
                float mn = fmaxf(m[q2][r], pm);
                alpha[q2][r] = __expf(m[q2][r] - mn);
                m[q2][r] = mn;
                #pragma unroll
                for (int ct4 = 0; ct4 < 4; ++ct4) s[q2][ct4][r] = __expf(s[q2][ct4][r] - mn);
                float rs = (s[q2][0][r] + s[q2][1][r]) + (s[q2][2][r] + s[q2][3][r]);
                DPPRED_SUM(rs);
                l[q2][r] = l[q2][r] * alpha[q2][r] + rs;
            }
        }
        #pragma unroll
        for (int q2 = 0; q2 < 2; ++q2)
            #pragma unroll
            for (int ct = 0; ct < 8; ++ct)
                #pragma unroll
                for (int r = 0; r < 4; ++r) o[q2][ct][r] *= alpha[q2][r];

        // P -> bf16, transpose via per-wave LDS (2-pass, wave-internal)
        bf16x8 pa[2][2];
        #pragma unroll
        for (int q2 = 0; q2 < 2; ++q2) {
            #pragma unroll
            for (int ct4 = 0; ct4 < 4; ++ct4)
                #pragma unroll
                for (int r = 0; r < 4; ++r)
                    Ps[wave][4 * hi + r][ct4 * 16 + lo] = f2bf(s[q2][ct4][r]);
            pa[q2][0] = *(const bf16x8*)&Ps[wave][lo][8 * hi];
            pa[q2][1] = *(const bf16x8*)&Ps[wave][lo][32 + 8 * hi];
        }

        // O += P V
        __builtin_amdgcn_s_setprio(1);
        #pragma unroll
        for (int ct = 0; ct < 8; ++ct) {
            const int row = ct * 16 + lo;
            #pragma unroll
            for (int half = 0; half < 2; ++half) {
                bf16x8 vf = *(const bf16x8*)&Vs[row * 64 + (((half * 4 + hi) ^ (row & 7)) * 8)];
                o[0][ct] = __builtin_amdgcn_mfma_f32_16x16x32_bf16(pa[0][half], vf, o[0][ct], 0, 0, 0);
                o[1][ct] = __builtin_amdgcn_mfma_f32_16x16x32_bf16(pa[1][half], vf, o[1][ct], 0, 0, 0);
            }
        }
        __builtin_amdgcn_s_setprio(0);
    }

    // write partial state: slot = b*36 + qt(qt+1)/2 + chunk
    const int slot = b * 36 + ((qt * (qt + 1)) >> 1) + chunk;
    float* op = Opart + (size_t)slot * 32768 + (size_t)(wave * 32) * 128;
    #pragma unroll
    for (int q2 = 0; q2 < 2; ++q2)
        #pragma unroll
        for (int ct = 0; ct < 8; ++ct)
            #pragma unroll
            for (int r = 0; r < 4; ++r)
                op[(16 * q2 + 4 * hi + r) * 128 + ct * 16 + lo] = o[q2][ct][r];
    if (lo == 0) {
        #pragma unroll
        for (int q2 = 0; q2 < 2; ++q2)
            #pragma unroll
            for (int r = 0; r < 4; ++r) {
                int base = slot * 512 + (wave * 32 + 16 * q2 + 4 * hi + r) * 2;
                MLpart[base]     = m[q2][r];
                MLpart[base + 1] = l[q2][r];
            }
    }
}

// ---------------------------------------------------------------------------
// Flash pass 2: merge <= 8 chunk partials. 512 blocks x 128 thr.
// ---------------------------------------------------------------------------
__launch_bounds__(128)
__global__ void attn2_kernel(const float* __restrict__ Opart,
                             const float* __restrict__ MLpart,
                             float* __restrict__ out) {
    const int bid = blockIdx.x;
    const int b   = bid & 7;
    const int qt  = (bid >> 3) & 7;
    const int sub = bid >> 6;              // 0..7
    const int nch = qt + 1;
    const int slot0 = b * 36 + ((qt * (qt + 1)) >> 1);

    const int tid  = threadIdx.x;
    const int row  = tid >> 2;             // 0..31
    const int h0   = (tid & 3) * 32;
    const int srow = sub * 32 + row;       // row within slot

    float M = -1e30f;
    for (int c = 0; c < nch; ++c)
        M = fmaxf(M, MLpart[(slot0 + c) * 512 + srow * 2]);
    float L = 0.f;
    for (int c = 0; c < nch; ++c) {
        float mc = MLpart[(slot0 + c) * 512 + srow * 2];
        float lc = MLpart[(slot0 + c) * 512 + srow * 2 + 1];
        L += lc * __expf(mc - M);
    }

    float4 acc[8];
    #pragma unroll
    for (int j = 0; j < 8; ++j) acc[j] = float4{0.f, 0.f, 0.f, 0.f};
    for (int c = 0; c < nch; ++c) {
        float wc = __expf(MLpart[(slot0 + c) * 512 + srow * 2] - M);
        const float4* src = (const float4*)(Opart + (size_t)(slot0 + c) * 32768 + (size_t)srow * 128 + h0);
        #pragma unroll
        for (int j = 0; j < 8; ++j) {
            float4 v = src[j];
            acc[j].x += wc * v.x; acc[j].y += wc * v.y;
            acc[j].z += wc * v.z; acc[j].w += wc * v.w;
        }
    }
    float inv = 1.f / L;
    float4* dst = (float4*)(out + ((size_t)b * T_ + qt * 256 + srow) * H_ + h0);
    #pragma unroll
    for (int j = 0; j < 8; ++j) {
        float4 v = acc[j];
        dst[j] = float4{v.x * inv, v.y * inv, v.z * inv, v.w * inv};
    }
}

extern "C" void kernel_launch(void* const* d_in, const int* in_sizes, int n_in,
                              void* d_out, int out_size, void* d_ws, size_t ws_size,
                              hipStream_t stream) {
    const float* x  = (const float*)d_in[0];
    const float* Wq = (const float*)d_in[1];
    const float* Wk = (const float*)d_in[2];
    const float* Wv = (const float*)d_in[3];
    float* out = (float*)d_out;

    char* ws = (char*)d_ws;
    unsigned short* Wt  = (unsigned short*)ws;                          // 0.75 MB
    unsigned short* qbf = (unsigned short*)(ws + (size_t)384 * 1024 * 2);
    unsigned short* kbf = qbf + (size_t)B_ * T_ * H_;
    unsigned short* vTf = kbf + (size_t)B_ * T_ * H_;
    float* Opart  = (float*)(vTf + (size_t)B_ * T_ * H_);               // 288*128KB = 36 MB
    float* MLpart = (float*)((char*)Opart + (size_t)288 * 32768 * 4);   // 0.56 MB

    wconv_kernel<<<(384 * 1024) / 256, 256, 0, stream>>>(Wq, Wk, Wv, Wt);
    gemm_kernel<<<(B_ * T_ / 64) * 2, 512, 0, stream>>>(x, Wt, qbf, kbf, vTf);
    attn1_kernel<<<512, 512, 0, stream>>>(qbf, kbf, vTf, Opart, MLpart);
    attn2_kernel<<<512, 128, 0, stream>>>(Opart, MLpart, out);
}

// Round 7
// 154.647 us; speedup vs baseline: 1.0081x; 1.0081x over previous
//
#include <hip/hip_runtime.h>
#include <hip/hip_bf16.h>

#define B_  8
#define T_  2048
#define C_  1024
#define H_  128

using f32x4  = __attribute__((ext_vector_type(4))) float;
using bf16x8 = __attribute__((ext_vector_type(8))) short;

__device__ __forceinline__ unsigned short f2bf(float f) {
    union { float f; unsigned u; } v; v.f = f;
    unsigned r = v.u + 0x7FFFu + ((v.u >> 16) & 1u);   // RNE
    return (unsigned short)(r >> 16);
}

// DPP cross-lane reduce within 16-lane rows (VALU-speed)
template<int C>
__device__ __forceinline__ float dppf(float v) {
    return __int_as_float(__builtin_amdgcn_update_dpp(0, __float_as_int(v), C, 0xF, 0xF, true));
}
#define DPPRED_MAX(v) { v = fmaxf(v, dppf<0xB1>(v)); v = fmaxf(v, dppf<0x4E>(v)); \
                        v = fmaxf(v, dppf<0x141>(v)); v = fmaxf(v, dppf<0x140>(v)); }
#define DPPRED_SUM(v) { v = v + dppf<0xB1>(v); v = v + dppf<0x4E>(v); \
                        v = v + dppf<0x141>(v); v = v + dppf<0x140>(v); }

// ---------------------------------------------------------------------------
// W{q,k,v} fp32 [1024][128] -> Wt bf16 [384 cols][1024 k], Wq pre-scaled 1/32
// ---------------------------------------------------------------------------
__global__ void wconv_kernel(const float* __restrict__ Wq,
                             const float* __restrict__ Wk,
                             const float* __restrict__ Wv,
                             unsigned short* __restrict__ Wt) {
    int id  = blockIdx.x * 256 + threadIdx.x;
    int col = id % 384;
    int k   = id / 384;
    const float* W = (col < 128) ? Wq : ((col < 256) ? Wk : Wv);
    float v = W[k * H_ + (col & 127)];
    if (col < 128) v *= 0.03125f;   // fold C^-0.5 into Wq (exact pow2)
    Wt[(size_t)col * C_ + k] = f2bf(v);
}

// ---------------------------------------------------------------------------
// Fused projection GEMM. Grid 1024 (512 row-tiles x 2 col-halves) x 256 thr
// (4 waves: 2r x 2c). Tile 32r x 192c, BK=64 (16 steps). 4 blocks/CU
// co-resident — barrier drains in one block overlap compute in the others.
// A (x fp32->bf16) staged in padded LDS dbuf; B panel shared by row-waves.
// ---------------------------------------------------------------------------
__launch_bounds__(256, 4)
__global__ void gemm_kernel(const float* __restrict__ x,
                            const unsigned short* __restrict__ Wt,
                            unsigned short* __restrict__ qb,
                            unsigned short* __restrict__ kb,
                            unsigned short* __restrict__ vT) {
    __shared__ unsigned short As[2][32][68];   // pad 64->68: rows shift 2 banks

    const int tid  = threadIdx.x;
    const int wave = tid >> 6;
    const int lane = tid & 63;
    const int lo = lane & 15, hi = lane >> 4;
    const int rb   = blockIdx.x >> 1;
    const int ch   = blockIdx.x & 1;
    const int row0 = rb * 32;
    const int col0 = ch * 192 + (wave & 1) * 96;
    const int wrow = (wave >> 1) * 16;

    const int srow = tid >> 3;                 // 0..31
    const int sk   = (tid & 7) * 8;            // 0..56
    const float* xsrc = x + (size_t)(row0 + srow) * C_ + sk;

    f32x4 acc[6];
    #pragma unroll
    for (int ct = 0; ct < 6; ++ct) acc[ct] = f32x4{0.f, 0.f, 0.f, 0.f};

    // prologue: stage step 0
    {
        float4 g0 = *(const float4*)(xsrc);
        float4 g1 = *(const float4*)(xsrc + 4);
        unsigned a0 = f2bf(g0.x) | ((unsigned)f2bf(g0.y) << 16);
        unsigned a1 = f2bf(g0.z) | ((unsigned)f2bf(g0.w) << 16);
        unsigned a2 = f2bf(g1.x) | ((unsigned)f2bf(g1.y) << 16);
        unsigned a3 = f2bf(g1.z) | ((unsigned)f2bf(g1.w) << 16);
        *(uint4*)&As[0][srow][sk] = uint4{a0, a1, a2, a3};
    }
    __syncthreads();

    for (int k = 0; k < 16; ++k) {
        const int cur = k & 1;

        // x loads for step k+1 (issued first; fly under B loads + MFMA)
        float4 g0, g1;
        if (k < 15) {
            g0 = *(const float4*)(xsrc + (k + 1) * 64);
            g1 = *(const float4*)(xsrc + (k + 1) * 64 + 4);
        }

        // B frags for this step (shared panel, read once per block per step)
        bf16x8 bf[6][2];
        #pragma unroll
        for (int ct = 0; ct < 6; ++ct) {
            const unsigned short* wp = Wt + (size_t)(col0 + ct * 16 + lo) * C_ + k * 64 + 8 * hi;
            bf[ct][0] = *(const bf16x8*)(wp);
            bf[ct][1] = *(const bf16x8*)(wp + 32);
        }

        // A frags from LDS
        bf16x8 af[2];
        #pragma unroll
        for (int kc = 0; kc < 2; ++kc)
            af[kc] = *(const bf16x8*)(&As[cur][wrow + lo][kc * 32 + 8 * hi]);

        #pragma unroll
        for (int kc = 0; kc < 2; ++kc)
            #pragma unroll
            for (int ct = 0; ct < 6; ++ct)
                acc[ct] = __builtin_amdgcn_mfma_f32_16x16x32_bf16(af[kc], bf[ct][kc], acc[ct], 0, 0, 0);

        if (k < 15) {
            unsigned a0 = f2bf(g0.x) | ((unsigned)f2bf(g0.y) << 16);
            unsigned a1 = f2bf(g0.z) | ((unsigned)f2bf(g0.w) << 16);
            unsigned a2 = f2bf(g1.x) | ((unsigned)f2bf(g1.y) << 16);
            unsigned a3 = f2bf(g1.z) | ((unsigned)f2bf(g1.w) << 16);
            *(uint4*)&As[cur ^ 1][srow][sk] = uint4{a0, a1, a2, a3};
        }
        __syncthreads();
    }

    #pragma unroll
    for (int ct = 0; ct < 6; ++ct) {
        int col = col0 + ct * 16 + lo;
        int head = col >> 7;
        int h = col & 127;
        #pragma unroll
        for (int r = 0; r < 4; ++r) {
            int rg = row0 + wrow + 4 * hi + r;
            unsigned short val = f2bf(acc[ct][r]);
            if (head == 0)      qb[(size_t)rg * H_ + h] = val;
            else if (head == 1) kb[(size_t)rg * H_ + h] = val;
            else {
                int b = rg >> 11, t = rg & (T_ - 1);
                vT[((size_t)b * H_ + h) * T_ + t] = val;
            }
        }
    }
}

// ---------------------------------------------------------------------------
// Flash pass 1 (R4 form). Block = 8 waves (512 thr); QBLK=256 (32 q-rows/wave);
// chunk = 256 kv = 4 x KV64 tiles. Grid 512 (heavy qt first), empties exit.
// K/V staged in XOR-swizzled LDS; reg-staged one tile ahead. Per-wave guard
// skips fully-masked tiles.
// ---------------------------------------------------------------------------
__launch_bounds__(512, 2)
__global__ void attn1_kernel(const unsigned short* __restrict__ qb,
                             const unsigned short* __restrict__ kb,
                             const unsigned short* __restrict__ vT,
                             float* __restrict__ Opart,
                             float* __restrict__ MLpart) {
    __shared__ unsigned short Ks[64 * 128];   // [kv][k], 16B chunks XOR-swizzled
    __shared__ unsigned short Vs[128 * 64];   // [h][kv], swizzled
    __shared__ unsigned short Ps[8][16][72];  // per-wave P transpose (2-pass)

    const int tid  = threadIdx.x;
    const int wave = tid >> 6;
    const int lane = tid & 63;
    const int lo = lane & 15, hi = lane >> 4;

    const int bid   = blockIdx.x;
    const int b     = bid & 7;
    const int chunk = (bid >> 3) & 7;
    const int qt    = 7 - (bid >> 6);
    if (chunk > qt) return;

    const int kv_begin = chunk << 8;
    const size_t bT = (size_t)b * T_;
    const int qrow0 = (qt << 8) + wave * 32;

    // staging assignment: K 2x16B chunks, V 2x16B chunks per thread
    const int krow = tid >> 3, kcol = (tid & 7) * 2;
    const int vrow = tid >> 2, vcol = (tid & 3) * 2;
    const unsigned short* kgsrc = kb + (bT + krow) * H_ + kcol * 8;
    const unsigned short* vgsrc = vT + ((size_t)b * H_ + vrow) * T_ + vcol * 8;
    unsigned short* kdst0 = &Ks[krow * 128 + ((kcol ^ (krow & 7)) * 8)];
    unsigned short* kdst1 = &Ks[krow * 128 + (((kcol + 1) ^ (krow & 7)) * 8)];
    unsigned short* vdst0 = &Vs[vrow * 64 + ((vcol ^ (vrow & 7)) * 8)];
    unsigned short* vdst1 = &Vs[vrow * 64 + (((vcol + 1) ^ (vrow & 7)) * 8)];

    // Q fragments (32 rows/wave)
    bf16x8 qf[2][4];
    #pragma unroll
    for (int q2 = 0; q2 < 2; ++q2)
        #pragma unroll
        for (int kc = 0; kc < 4; ++kc)
            qf[q2][kc] = *(const bf16x8*)(qb + (bT + qrow0 + 16 * q2 + lo) * H_ + kc * 32 + 8 * hi);

    float m[2][4], l[2][4];
    f32x4 o[2][8];
    #pragma unroll
    for (int q2 = 0; q2 < 2; ++q2)
        #pragma unroll
        for (int r = 0; r < 4; ++r) { m[q2][r] = -1e30f; l[q2][r] = 0.f; }
    #pragma unroll
    for (int q2 = 0; q2 < 2; ++q2)
        #pragma unroll
        for (int ct = 0; ct < 8; ++ct) o[q2][ct] = f32x4{0.f, 0.f, 0.f, 0.f};

    // prologue: stage-regs for tile 0
    uint4 kr0 = *(const uint4*)(kgsrc + (size_t)kv_begin * H_);
    uint4 kr1 = *(const uint4*)(kgsrc + (size_t)kv_begin * H_ + 8);
    uint4 vr0 = *(const uint4*)(vgsrc + kv_begin);
    uint4 vr1 = *(const uint4*)(vgsrc + kv_begin + 8);

    for (int t = 0; t < 4; ++t) {
        const int kv0 = kv_begin + t * 64;
        __syncthreads();                       // all reads of prev tile done
        *(uint4*)kdst0 = kr0;
        *(uint4*)kdst1 = kr1;
        *(uint4*)vdst0 = vr0;
        *(uint4*)vdst1 = vr1;
        __syncthreads();                       // tile staged
        if (t < 3) {                           // issue next-tile loads now
            const int kvn = kv0 + 64;
            kr0 = *(const uint4*)(kgsrc + (size_t)kvn * H_);
            kr1 = *(const uint4*)(kgsrc + (size_t)kvn * H_ + 8);
            vr0 = *(const uint4*)(vgsrc + kvn);
            vr1 = *(const uint4*)(vgsrc + kvn + 8);
        }
        if (kv0 > qrow0 + 31) continue;        // fully masked for this wave

        // S = Q K^T
        f32x4 s[2][4];
        #pragma unroll
        for (int q2 = 0; q2 < 2; ++q2)
            #pragma unroll
            for (int ct4 = 0; ct4 < 4; ++ct4) s[q2][ct4] = f32x4{0.f, 0.f, 0.f, 0.f};
        __builtin_amdgcn_s_setprio(1);
        #pragma unroll
        for (int ct4 = 0; ct4 < 4; ++ct4) {
            const int row = ct4 * 16 + lo;
            #pragma unroll
            for (int kc = 0; kc < 4; ++kc) {
                bf16x8 kf = *(const bf16x8*)&Ks[row * 128 + (((kc * 4 + hi) ^ (row & 7)) * 8)];
                s[0][ct4] = __builtin_amdgcn_mfma_f32_16x16x32_bf16(qf[0][kc], kf, s[0][ct4], 0, 0, 0);
                s[1][ct4] = __builtin_amdgcn_mfma_f32_16x16x32_bf16(qf[1][kc], kf, s[1][ct4], 0, 0, 0);
            }
        }
        __builtin_amdgcn_s_setprio(0);

        // causal mask (diagonal tiles only)
        if (kv0 + 63 >= qrow0) {
            #pragma unroll
            for (int q2 = 0; q2 < 2; ++q2)
                #pragma unroll
                for (int ct4 = 0; ct4 < 4; ++ct4)
                    #pragma unroll
                    for (int r = 0; r < 4; ++r)
                        if (kv0 + ct4 * 16 + lo > qrow0 + 16 * q2 + 4 * hi + r)
                            s[q2][ct4][r] = -1e30f;
        }

        // online softmax (DPP reductions within 16-lane rows)
        float alpha[2][4];
        #pragma unroll
        for (int q2 = 0; q2 < 2; ++q2) {
            #pragma unroll
            for (int r = 0; r < 4; ++r) {
                float pm = fmaxf(fmaxf(s[q2][0][r], s[q2][1][r]), fmaxf(s[q2][2][r], s[q2][3][r]));
                DPPRED_MAX(pm);
                float mn = fmaxf(m[q2][r], pm);
                alpha[q2][r] = __expf(m[q2][r] - mn);
                m[q2][r] = mn;
                #pragma unroll
                for (int ct4 = 0; ct4 < 4; ++ct4) s[q2][ct4][r] = __expf(s[q2][ct4][r] - mn);
                float rs = (s[q2][0][r] + s[q2][1][r]) + (s[q2][2][r] + s[q2][3][r]);
                DPPRED_SUM(rs);
                l[q2][r] = l[q2][r] * alpha[q2][r] + rs;
            }
        }
        #pragma unroll
        for (int q2 = 0; q2 < 2; ++q2)
            #pragma unroll
            for (int ct = 0; ct < 8; ++ct)
                #pragma unroll
                for (int r = 0; r < 4; ++r) o[q2][ct][r] *= alpha[q2][r];

        // P -> bf16, transpose via per-wave LDS (2-pass, wave-internal)
        bf16x8 pa[2][2];
        #pragma unroll
        for (int q2 = 0; q2 < 2; ++q2) {
            #pragma unroll
            for (int ct4 = 0; ct4 < 4; ++ct4)
                #pragma unroll
                for (int r = 0; r < 4; ++r)
                    Ps[wave][4 * hi + r][ct4 * 16 + lo] = f2bf(s[q2][ct4][r]);
            pa[q2][0] = *(const bf16x8*)&Ps[wave][lo][8 * hi];
            pa[q2][1] = *(const bf16x8*)&Ps[wave][lo][32 + 8 * hi];
        }

        // O += P V
        __builtin_amdgcn_s_setprio(1);
        #pragma unroll
        for (int ct = 0; ct < 8; ++ct) {
            const int row = ct * 16 + lo;
            #pragma unroll
            for (int half = 0; half < 2; ++half) {
                bf16x8 vf = *(const bf16x8*)&Vs[row * 64 + (((half * 4 + hi) ^ (row & 7)) * 8)];
                o[0][ct] = __builtin_amdgcn_mfma_f32_16x16x32_bf16(pa[0][half], vf, o[0][ct], 0, 0, 0);
                o[1][ct] = __builtin_amdgcn_mfma_f32_16x16x32_bf16(pa[1][half], vf, o[1][ct], 0, 0, 0);
            }
        }
        __builtin_amdgcn_s_setprio(0);
    }

    // write partial state: slot = b*36 + qt(qt+1)/2 + chunk
    const int slot = b * 36 + ((qt * (qt + 1)) >> 1) + chunk;
    float* op = Opart + (size_t)slot * 32768 + (size_t)(wave * 32) * 128;
    #pragma unroll
    for (int q2 = 0; q2 < 2; ++q2)
        #pragma unroll
        for (int ct = 0; ct < 8; ++ct)
            #pragma unroll
            for (int r = 0; r < 4; ++r)
                op[(16 * q2 + 4 * hi + r) * 128 + ct * 16 + lo] = o[q2][ct][r];
    if (lo == 0) {
        #pragma unroll
        for (int q2 = 0; q2 < 2; ++q2)
            #pragma unroll
            for (int r = 0; r < 4; ++r) {
                int base = slot * 512 + (wave * 32 + 16 * q2 + 4 * hi + r) * 2;
                MLpart[base]     = m[q2][r];
                MLpart[base + 1] = l[q2][r];
            }
    }
}

// ---------------------------------------------------------------------------
// Flash pass 2: merge <= 8 chunk partials. 512 blocks x 128 thr.
// ---------------------------------------------------------------------------
__launch_bounds__(128)
__global__ void attn2_kernel(const float* __restrict__ Opart,
                             const float* __restrict__ MLpart,
                             float* __restrict__ out) {
    const int bid = blockIdx.x;
    const int b   = bid & 7;
    const int qt  = (bid >> 3) & 7;
    const int sub = bid >> 6;              // 0..7
    const int nch = qt + 1;
    const int slot0 = b * 36 + ((qt * (qt + 1)) >> 1);

    const int tid  = threadIdx.x;
    const int row  = tid >> 2;             // 0..31
    const int h0   = (tid & 3) * 32;
    const int srow = sub * 32 + row;       // row within slot

    float M = -1e30f;
    for (int c = 0; c < nch; ++c)
        M = fmaxf(M, MLpart[(slot0 + c) * 512 + srow * 2]);
    float L = 0.f;
    for (int c = 0; c < nch; ++c) {
        float mc = MLpart[(slot0 + c) * 512 + srow * 2];
        float lc = MLpart[(slot0 + c) * 512 + srow * 2 + 1];
        L += lc * __expf(mc - M);
    }

    float4 acc[8];
    #pragma unroll
    for (int j = 0; j < 8; ++j) acc[j] = float4{0.f, 0.f, 0.f, 0.f};
    for (int c = 0; c < nch; ++c) {
        float wc = __expf(MLpart[(slot0 + c) * 512 + srow * 2] - M);
        const float4* src = (const float4*)(Opart + (size_t)(slot0 + c) * 32768 + (size_t)srow * 128 + h0);
        #pragma unroll
        for (int j = 0; j < 8; ++j) {
            float4 v = src[j];
            acc[j].x += wc * v.x; acc[j].y += wc * v.y;
            acc[j].z += wc * v.z; acc[j].w += wc * v.w;
        }
    }
    float inv = 1.f / L;
    float4* dst = (float4*)(out + ((size_t)b * T_ + qt * 256 + srow) * H_ + h0);
    #pragma unroll
    for (int j = 0; j < 8; ++j) {
        float4 v = acc[j];
        dst[j] = float4{v.x * inv, v.y * inv, v.z * inv, v.w * inv};
    }
}

extern "C" void kernel_launch(void* const* d_in, const int* in_sizes, int n_in,
                              void* d_out, int out_size, void* d_ws, size_t ws_size,
                              hipStream_t stream) {
    const float* x  = (const float*)d_in[0];
    const float* Wq = (const float*)d_in[1];
    const float* Wk = (const float*)d_in[2];
    const float* Wv = (const float*)d_in[3];
    float* out = (float*)d_out;

    char* ws = (char*)d_ws;
    unsigned short* Wt  = (unsigned short*)ws;                          // 0.75 MB
    unsigned short* qbf = (unsigned short*)(ws + (size_t)384 * 1024 * 2);
    unsigned short* kbf = qbf + (size_t)B_ * T_ * H_;
    unsigned short* vTf = kbf + (size_t)B_ * T_ * H_;
    float* Opart  = (float*)(vTf + (size_t)B_ * T_ * H_);               // 288*128KB = 36 MB
    float* MLpart = (float*)((char*)Opart + (size_t)288 * 32768 * 4);   // 0.56 MB

    wconv_kernel<<<(384 * 1024) / 256, 256, 0, stream>>>(Wq, Wk, Wv, Wt);
    gemm_kernel<<<(B_ * T_ / 32) * 2, 256, 0, stream>>>(x, Wt, qbf, kbf, vTf);
    attn1_kernel<<<512, 512, 0, stream>>>(qbf, kbf, vTf, Opart, MLpart);
    attn2_kernel<<<512, 128, 0, stream>>>(Opart, MLpart, out);
}

// Round 8
// 88.844 us; speedup vs baseline: 1.7547x; 1.7407x over previous
//
#include <hip/hip_runtime.h>
#include <hip/hip_bf16.h>

#define B_  8
#define T_  2048
#define C_  1024
#define H_  128

using f32x4  = __attribute__((ext_vector_type(4))) float;
using bf16x8 = __attribute__((ext_vector_type(8))) short;

__device__ __forceinline__ unsigned short f2bf(float f) {
    union { float f; unsigned u; } v; v.f = f;
    unsigned r = v.u + 0x7FFFu + ((v.u >> 16) & 1u);   // RNE
    return (unsigned short)(r >> 16);
}

// DPP cross-lane reduce within 16-lane rows (VALU-speed)
template<int C>
__device__ __forceinline__ float dppf(float v) {
    return __int_as_float(__builtin_amdgcn_update_dpp(0, __float_as_int(v), C, 0xF, 0xF, true));
}
#define DPPRED_MAX(v) { v = fmaxf(v, dppf<0xB1>(v)); v = fmaxf(v, dppf<0x4E>(v)); \
                        v = fmaxf(v, dppf<0x141>(v)); v = fmaxf(v, dppf<0x140>(v)); }
#define DPPRED_SUM(v) { v = v + dppf<0xB1>(v); v = v + dppf<0x4E>(v); \
                        v = v + dppf<0x141>(v); v = v + dppf<0x140>(v); }

// ---------------------------------------------------------------------------
// W{q,k,v} fp32 [1024][128] -> Wt2 K-TILED bf16: Wt2[k>>5][col][k&31]
// (each 384x32 B-tile = contiguous 24 KB => gemm staging is a pure stream).
// Wq pre-scaled by 1/32.
// ---------------------------------------------------------------------------
__global__ void wconv_kernel(const float* __restrict__ Wq,
                             const float* __restrict__ Wk,
                             const float* __restrict__ Wv,
                             unsigned short* __restrict__ Wt) {
    int id  = blockIdx.x * 256 + threadIdx.x;
    int col = id % 384;
    int k   = id / 384;
    const float* W = (col < 128) ? Wq : ((col < 256) ? Wk : Wv);
    float v = W[k * H_ + (col & 127)];
    if (col < 128) v *= 0.03125f;   // fold C^-0.5 into Wq (exact pow2)
    Wt[(size_t)(k >> 5) * 12288 + col * 32 + (k & 31)] = f2bf(v);
}

// ---------------------------------------------------------------------------
// Fused projection GEMM, canonical LDS-staged form. Grid 512 x 256 thr
// (4 waves; wave = 32r x 96c, acc[2][6]). BK=32, 32 K-steps.
// Per step: B-tile 24 KB streamed contiguously into LDS dbuf (shared by all
// waves, no gather, no duplication); A-tile x fp32->bf16 reg-staged (2 KB).
// Frag reads are linear conflict-free ds_read_b128. One barrier per step.
// ---------------------------------------------------------------------------
__launch_bounds__(256, 2)
__global__ void gemm_kernel(const float* __restrict__ x,
                            const unsigned short* __restrict__ Wt,
                            unsigned short* __restrict__ qb,
                            unsigned short* __restrict__ kb,
                            unsigned short* __restrict__ vT) {
    __shared__ unsigned short Bs[2][12288];    // [col][k32], 24 KB per buf
    __shared__ unsigned short As[2][32][32];   // [row][k32], 2 KB per buf

    const int tid  = threadIdx.x;
    const int wave = tid >> 6;
    const int lane = tid & 63;
    const int lo = lane & 15, hi = lane >> 4;
    const int row0  = blockIdx.x * 32;
    const int col0w = wave * 96;               // wave's col panel (distinct)

    const int srow = tid >> 3;                 // A staging: row 0..31
    const int sk4  = (tid & 7) * 4;            // A staging: 4 fp32
    const float* xsrc = x + (size_t)(row0 + srow) * C_ + sk4;

    f32x4 acc[2][6];
    #pragma unroll
    for (int rt = 0; rt < 2; ++rt)
        #pragma unroll
        for (int ct = 0; ct < 6; ++ct)
            acc[rt][ct] = f32x4{0.f, 0.f, 0.f, 0.f};

    // prologue: stage step 0
    {
        const unsigned short* bsrc = Wt + (size_t)tid * 8;
        #pragma unroll
        for (int j = 0; j < 6; ++j)
            *(uint4*)&Bs[0][tid * 8 + j * 2048] = *(const uint4*)(bsrc + j * 2048);
        float4 f = *(const float4*)(xsrc);
        unsigned a0 = f2bf(f.x) | ((unsigned)f2bf(f.y) << 16);
        unsigned a1 = f2bf(f.z) | ((unsigned)f2bf(f.w) << 16);
        *(uint2*)&As[0][srow][sk4] = uint2{a0, a1};
    }
    __syncthreads();

    for (int k = 0; k < 32; ++k) {
        const int cur = k & 1;

        // issue step k+1 global loads (contiguous stream; fly under compute)
        uint4 br[6];
        float4 xf;
        if (k < 31) {
            const unsigned short* bsrc = Wt + (size_t)(k + 1) * 12288 + tid * 8;
            #pragma unroll
            for (int j = 0; j < 6; ++j)
                br[j] = *(const uint4*)(bsrc + j * 2048);
            xf = *(const float4*)(xsrc + (k + 1) * 32);
        }

        // fragments from LDS (linear, conflict-free)
        bf16x8 af[2], bfr[6];
        #pragma unroll
        for (int rt = 0; rt < 2; ++rt)
            af[rt] = *(const bf16x8*)&As[cur][rt * 16 + lo][hi * 8];
        #pragma unroll
        for (int ct = 0; ct < 6; ++ct)
            bfr[ct] = *(const bf16x8*)&Bs[cur][(col0w + ct * 16 + lo) * 32 + hi * 8];

        __builtin_amdgcn_s_setprio(1);
        #pragma unroll
        for (int ct = 0; ct < 6; ++ct)
            #pragma unroll
            for (int rt = 0; rt < 2; ++rt)
                acc[rt][ct] = __builtin_amdgcn_mfma_f32_16x16x32_bf16(af[rt], bfr[ct], acc[rt][ct], 0, 0, 0);
        __builtin_amdgcn_s_setprio(0);

        // stage step k+1 into the other buffer
        if (k < 31) {
            #pragma unroll
            for (int j = 0; j < 6; ++j)
                *(uint4*)&Bs[cur ^ 1][tid * 8 + j * 2048] = br[j];
            unsigned a0 = f2bf(xf.x) | ((unsigned)f2bf(xf.y) << 16);
            unsigned a1 = f2bf(xf.z) | ((unsigned)f2bf(xf.w) << 16);
            *(uint2*)&As[cur ^ 1][srow][sk4] = uint2{a0, a1};
        }
        __syncthreads();
    }

    // epilogue
    #pragma unroll
    for (int ct = 0; ct < 6; ++ct) {
        int col = col0w + ct * 16 + lo;
        int head = col >> 7;
        int h = col & 127;
        #pragma unroll
        for (int rt = 0; rt < 2; ++rt) {
            #pragma unroll
            for (int r = 0; r < 4; ++r) {
                int rg = row0 + rt * 16 + 4 * hi + r;
                unsigned short val = f2bf(acc[rt][ct][r]);
                if (head == 0)      qb[(size_t)rg * H_ + h] = val;
                else if (head == 1) kb[(size_t)rg * H_ + h] = val;
                else {
                    int b = rg >> 11, t = rg & (T_ - 1);
                    vT[((size_t)b * H_ + h) * T_ + t] = val;
                }
            }
        }
    }
}

// ---------------------------------------------------------------------------
// Flash pass 1 (R4 form, unchanged). Block = 8 waves (512 thr); QBLK=256;
// chunk = 256 kv = 4 x KV64 tiles. Grid 512, empties exit.
// ---------------------------------------------------------------------------
__launch_bounds__(512, 2)
__global__ void attn1_kernel(const unsigned short* __restrict__ qb,
                             const unsigned short* __restrict__ kb,
                             const unsigned short* __restrict__ vT,
                             float* __restrict__ Opart,
                             float* __restrict__ MLpart) {
    __shared__ unsigned short Ks[64 * 128];   // [kv][k], 16B chunks XOR-swizzled
    __shared__ unsigned short Vs[128 * 64];   // [h][kv], swizzled
    __shared__ unsigned short Ps[8][16][72];  // per-wave P transpose (2-pass)

    const int tid  = threadIdx.x;
    const int wave = tid >> 6;
    const int lane = tid & 63;
    const int lo = lane & 15, hi = lane >> 4;

    const int bid   = blockIdx.x;
    const int b     = bid & 7;
    const int chunk = (bid >> 3) & 7;
    const int qt    = 7 - (bid >> 6);
    if (chunk > qt) return;

    const int kv_begin = chunk << 8;
    const size_t bT = (size_t)b * T_;
    const int qrow0 = (qt << 8) + wave * 32;

    const int krow = tid >> 3, kcol = (tid & 7) * 2;
    const int vrow = tid >> 2, vcol = (tid & 3) * 2;
    const unsigned short* kgsrc = kb + (bT + krow) * H_ + kcol * 8;
    const unsigned short* vgsrc = vT + ((size_t)b * H_ + vrow) * T_ + vcol * 8;
    unsigned short* kdst0 = &Ks[krow * 128 + ((kcol ^ (krow & 7)) * 8)];
    unsigned short* kdst1 = &Ks[krow * 128 + (((kcol + 1) ^ (krow & 7)) * 8)];
    unsigned short* vdst0 = &Vs[vrow * 64 + ((vcol ^ (vrow & 7)) * 8)];
    unsigned short* vdst1 = &Vs[vrow * 64 + (((vcol + 1) ^ (vrow & 7)) * 8)];

    bf16x8 qf[2][4];
    #pragma unroll
    for (int q2 = 0; q2 < 2; ++q2)
        #pragma unroll
        for (int kc = 0; kc < 4; ++kc)
            qf[q2][kc] = *(const bf16x8*)(qb + (bT + qrow0 + 16 * q2 + lo) * H_ + kc * 32 + 8 * hi);

    float m[2][4], l[2][4];
    f32x4 o[2][8];
    #pragma unroll
    for (int q2 = 0; q2 < 2; ++q2)
        #pragma unroll
        for (int r = 0; r < 4; ++r) { m[q2][r] = -1e30f; l[q2][r] = 0.f; }
    #pragma unroll
    for (int q2 = 0; q2 < 2; ++q2)
        #pragma unroll
        for (int ct = 0; ct < 8; ++ct) o[q2][ct] = f32x4{0.f, 0.f, 0.f, 0.f};

    uint4 kr0 = *(const uint4*)(kgsrc + (size_t)kv_begin * H_);
    uint4 kr1 = *(const uint4*)(kgsrc + (size_t)kv_begin * H_ + 8);
    uint4 vr0 = *(const uint4*)(vgsrc + kv_begin);
    uint4 vr1 = *(const uint4*)(vgsrc + kv_begin + 8);

    for (int t = 0; t < 4; ++t) {
        const int kv0 = kv_begin + t * 64;
        __syncthreads();
        *(uint4*)kdst0 = kr0;
        *(uint4*)kdst1 = kr1;
        *(uint4*)vdst0 = vr0;
        *(uint4*)vdst1 = vr1;
        __syncthreads();
        if (t < 3) {
            const int kvn = kv0 + 64;
            kr0 = *(const uint4*)(kgsrc + (size_t)kvn * H_);
            kr1 = *(const uint4*)(kgsrc + (size_t)kvn * H_ + 8);
            vr0 = *(const uint4*)(vgsrc + kvn);
            vr1 = *(const uint4*)(vgsrc + kvn + 8);
        }
        if (kv0 > qrow0 + 31) continue;

        f32x4 s[2][4];
        #pragma unroll
        for (int q2 = 0; q2 < 2; ++q2)
            #pragma unroll
            for (int ct4 = 0; ct4 < 4; ++ct4) s[q2][ct4] = f32x4{0.f, 0.f, 0.f, 0.f};
        __builtin_amdgcn_s_setprio(1);
        #pragma unroll
        for (int ct4 = 0; ct4 < 4; ++ct4) {
            const int row = ct4 * 16 + lo;
            #pragma unroll
            for (int kc = 0; kc < 4; ++kc) {
                bf16x8 kf = *(const bf16x8*)&Ks[row * 128 + (((kc * 4 + hi) ^ (row & 7)) * 8)];
                s[0][ct4] = __builtin_amdgcn_mfma_f32_16x16x32_bf16(qf[0][kc], kf, s[0][ct4], 0, 0, 0);
                s[1][ct4] = __builtin_amdgcn_mfma_f32_16x16x32_bf16(qf[1][kc], kf, s[1][ct4], 0, 0, 0);
            }
        }
        __builtin_amdgcn_s_setprio(0);

        if (kv0 + 63 >= qrow0) {
            #pragma unroll
            for (int q2 = 0; q2 < 2; ++q2)
                #pragma unroll
                for (int ct4 = 0; ct4 < 4; ++ct4)
                    #pragma unroll
                    for (int r = 0; r < 4; ++r)
                        if (kv0 + ct4 * 16 + lo > qrow0 + 16 * q2 + 4 * hi + r)
                            s[q2][ct4][r] = -1e30f;
        }

        float alpha[2][4];
        #pragma unroll
        for (int q2 = 0; q2 < 2; ++q2) {
            #pragma unroll
            for (int r = 0; r < 4; ++r) {
                float pm = fmaxf(fmaxf(s[q2][0][r], s[q2][1][r]), fmaxf(s[q2][2][r], s[q2][3][r]));
                DPPRED_MAX(pm);
                float mn = fmaxf(m[q2][r], pm);
                alpha[q2][r] = __expf(m[q2][r] - mn);
                m[q2][r] = mn;
                #pragma unroll
                for (int ct4 = 0; ct4 < 4; ++ct4) s[q2][ct4][r] = __expf(s[q2][ct4][r] - mn);
                float rs = (s[q2][0][r] + s[q2][1][r]) + (s[q2][2][r] + s[q2][3][r]);
                DPPRED_SUM(rs);
                l[q2][r] = l[q2][r] * alpha[q2][r] + rs;
            }
        }
        #pragma unroll
        for (int q2 = 0; q2 < 2; ++q2)
            #pragma unroll
            for (int ct = 0; ct < 8; ++ct)
                #pragma unroll
                for (int r = 0; r < 4; ++r) o[q2][ct][r] *= alpha[q2][r];

        bf16x8 pa[2][2];
        #pragma unroll
        for (int q2 = 0; q2 < 2; ++q2) {
            #pragma unroll
            for (int ct4 = 0; ct4 < 4; ++ct4)
                #pragma unroll
                for (int r = 0; r < 4; ++r)
                    Ps[wave][4 * hi + r][ct4 * 16 + lo] = f2bf(s[q2][ct4][r]);
            pa[q2][0] = *(const bf16x8*)&Ps[wave][lo][8 * hi];
            pa[q2][1] = *(const bf16x8*)&Ps[wave][lo][32 + 8 * hi];
        }

        __builtin_amdgcn_s_setprio(1);
        #pragma unroll
        for (int ct = 0; ct < 8; ++ct) {
            const int row = ct * 16 + lo;
            #pragma unroll
            for (int half = 0; half < 2; ++half) {
                bf16x8 vf = *(const bf16x8*)&Vs[row * 64 + (((half * 4 + hi) ^ (row & 7)) * 8)];
                o[0][ct] = __builtin_amdgcn_mfma_f32_16x16x32_bf16(pa[0][half], vf, o[0][ct], 0, 0, 0);
                o[1][ct] = __builtin_amdgcn_mfma_f32_16x16x32_bf16(pa[1][half], vf, o[1][ct], 0, 0, 0);
            }
        }
        __builtin_amdgcn_s_setprio(0);
    }

    const int slot = b * 36 + ((qt * (qt + 1)) >> 1) + chunk;
    float* op = Opart + (size_t)slot * 32768 + (size_t)(wave * 32) * 128;
    #pragma unroll
    for (int q2 = 0; q2 < 2; ++q2)
        #pragma unroll
        for (int ct = 0; ct < 8; ++ct)
            #pragma unroll
            for (int r = 0; r < 4; ++r)
                op[(16 * q2 + 4 * hi + r) * 128 + ct * 16 + lo] = o[q2][ct][r];
    if (lo == 0) {
        #pragma unroll
        for (int q2 = 0; q2 < 2; ++q2)
            #pragma unroll
            for (int r = 0; r < 4; ++r) {
                int base = slot * 512 + (wave * 32 + 16 * q2 + 4 * hi + r) * 2;
                MLpart[base]     = m[q2][r];
                MLpart[base + 1] = l[q2][r];
            }
    }
}

// ---------------------------------------------------------------------------
// Flash pass 2: merge <= 8 chunk partials. 512 blocks x 128 thr.
// ---------------------------------------------------------------------------
__launch_bounds__(128)
__global__ void attn2_kernel(const float* __restrict__ Opart,
                             const float* __restrict__ MLpart,
                             float* __restrict__ out) {
    const int bid = blockIdx.x;
    const int b   = bid & 7;
    const int qt  = (bid >> 3) & 7;
    const int sub = bid >> 6;              // 0..7
    const int nch = qt + 1;
    const int slot0 = b * 36 + ((qt * (qt + 1)) >> 1);

    const int tid  = threadIdx.x;
    const int row  = tid >> 2;             // 0..31
    const int h0   = (tid & 3) * 32;
    const int srow = sub * 32 + row;       // row within slot

    float M = -1e30f;
    for (int c = 0; c < nch; ++c)
        M = fmaxf(M, MLpart[(slot0 + c) * 512 + srow * 2]);
    float L = 0.f;
    for (int c = 0; c < nch; ++c) {
        float mc = MLpart[(slot0 + c) * 512 + srow * 2];
        float lc = MLpart[(slot0 + c) * 512 + srow * 2 + 1];
        L += lc * __expf(mc - M);
    }

    float4 acc[8];
    #pragma unroll
    for (int j = 0; j < 8; ++j) acc[j] = float4{0.f, 0.f, 0.f, 0.f};
    for (int c = 0; c < nch; ++c) {
        float wc = __expf(MLpart[(slot0 + c) * 512 + srow * 2] - M);
        const float4* src = (const float4*)(Opart + (size_t)(slot0 + c) * 32768 + (size_t)srow * 128 + h0);
        #pragma unroll
        for (int j = 0; j < 8; ++j) {
            float4 v = src[j];
            acc[j].x += wc * v.x; acc[j].y += wc * v.y;
            acc[j].z += wc * v.z; acc[j].w += wc * v.w;
        }
    }
    float inv = 1.f / L;
    float4* dst = (float4*)(out + ((size_t)b * T_ + qt * 256 + srow) * H_ + h0);
    #pragma unroll
    for (int j = 0; j < 8; ++j) {
        float4 v = acc[j];
        dst[j] = float4{v.x * inv, v.y * inv, v.z * inv, v.w * inv};
    }
}

extern "C" void kernel_launch(void* const* d_in, const int* in_sizes, int n_in,
                              void* d_out, int out_size, void* d_ws, size_t ws_size,
                              hipStream_t stream) {
    const float* x  = (const float*)d_in[0];
    const float* Wq = (const float*)d_in[1];
    const float* Wk = (const float*)d_in[2];
    const float* Wv = (const float*)d_in[3];
    float* out = (float*)d_out;

    char* ws = (char*)d_ws;
    unsigned short* Wt  = (unsigned short*)ws;                          // 0.75 MB
    unsigned short* qbf = (unsigned short*)(ws + (size_t)384 * 1024 * 2);
    unsigned short* kbf = qbf + (size_t)B_ * T_ * H_;
    unsigned short* vTf = kbf + (size_t)B_ * T_ * H_;
    float* Opart  = (float*)(vTf + (size_t)B_ * T_ * H_);               // 36 MB
    float* MLpart = (float*)((char*)Opart + (size_t)288 * 32768 * 4);   // 0.56 MB

    wconv_kernel<<<(384 * 1024) / 256, 256, 0, stream>>>(Wq, Wk, Wv, Wt);
    gemm_kernel<<<B_ * T_ / 32, 256, 0, stream>>>(x, Wt, qbf, kbf, vTf);
    attn1_kernel<<<512, 512, 0, stream>>>(qbf, kbf, vTf, Opart, MLpart);
    attn2_kernel<<<512, 128, 0, stream>>>(Opart, MLpart, out);
}